// Round 9
// baseline (195.765 us; speedup 1.0000x reference)
//
#include <hip/hip_runtime.h>
#include <hip/hip_bf16.h>
#include <cstddef>
#include <cstdint>

// B=2, S=2048, D=1024, H=16, KVH=4, hd=64. window from d_in[9].

typedef short v8s __attribute__((ext_vector_type(8)));
typedef float v4f __attribute__((ext_vector_type(4)));

// Exact RNE fp32->bf16 for FINITE values (no NaN path): 3 VALU ops.
__device__ __forceinline__ ushort b1(float a) {
  uint u = __float_as_uint(a);
  return (ushort)((u + 0x7FFFu + ((u >> 16) & 1u)) >> 16);
}
__device__ __forceinline__ uint bpack(float lo, float hi) {
  uint ul = __float_as_uint(lo), uh = __float_as_uint(hi);
  ul = (ul + 0x7FFFu + ((ul >> 16) & 1u)) >> 16;
  uh = (uh + 0x7FFFu + ((uh >> 16) & 1u)) & 0xFFFF0000u;
  return ul | uh;
}

// async global->LDS 16B/lane (wave-uniform LDS base + lane*16).
__device__ __forceinline__ void async16(const ushort* g, ushort* l) {
  __builtin_amdgcn_global_load_lds(
      (__attribute__((address_space(1))) void*)(uintptr_t)(const void*)g,
      (__attribute__((address_space(3))) void*)(uintptr_t)(void*)l, 16, 0, 0);
}

// ---------------- merged prep: x-cvt+gates | cs pack | 4 weight transposes --
__global__ __launch_bounds__(256) void prep_all(
    const float* __restrict__ x, ushort* __restrict__ xb,
    const float* __restrict__ Wg, float* __restrict__ gates,
    const float* __restrict__ cosp, const float* __restrict__ sinp,
    float2* __restrict__ cs,
    const float* __restrict__ Wq, const float* __restrict__ Wk,
    const float* __restrict__ Wv, const float* __restrict__ Wo,
    ushort* __restrict__ Wqt, ushort* __restrict__ Wkt,
    ushort* __restrict__ Wvt, ushort* __restrict__ Wot)
{
  const int bx = blockIdx.x, t = threadIdx.x;
  if (bx < 4096) {
    const float* row = x + (size_t)bx * 1024;
    float4 v = *(const float4*)(row + t * 4);
    ushort4 o;
    o.x = b1(v.x); o.y = b1(v.y); o.z = b1(v.z); o.w = b1(v.w);
    *(ushort4*)(xb + (size_t)bx * 1024 + t * 4) = o;
    if (t < 4) {
      float g = 0.f;
#pragma unroll
      for (int i = 0; i < 12; ++i) g += row[i] * Wg[i * 4 + t];
      gates[bx * 4 + t] = 3.0f / (1.0f + __expf(-g));
    }
    return;
  }
  if (bx < 4352) {
    const int i = (bx - 4096) * 256 + t;
    cs[i] = make_float2(cosp[i], sinp[i]);
    return;
  }
  __shared__ ushort tile[32][33];
  int u = bx - 4352;
  const float* W; ushort* Wt; int N, xx, yy;
  if (u < 1024)      { W = Wq; Wt = Wqt; N = 1024; xx = u & 31; yy = u >> 5; }
  else if (u < 2048) { u -= 1024; W = Wo; Wt = Wot; N = 1024; xx = u & 31; yy = u >> 5; }
  else if (u < 2304) { u -= 2048; W = Wk; Wt = Wkt; N = 256;  xx = u & 7;  yy = u >> 3; }
  else               { u -= 2304; W = Wv; Wt = Wvt; N = 256;  xx = u & 7;  yy = u >> 3; }
  const int n0 = xx * 32, k0 = yy * 32;
  const int tx = t & 31, ty = t >> 5;
#pragma unroll
  for (int i = 0; i < 4; ++i) {
    const int k = ty + i * 8;
    tile[k][tx] = b1(W[(size_t)(k0 + k) * N + n0 + tx]);
  }
  __syncthreads();
#pragma unroll
  for (int i = 0; i < 4; ++i) {
    const int n = ty + i * 8;
    Wt[(size_t)(n0 + n) * 1024 + k0 + tx] = tile[tx][n];
  }
}

// ---------------- GEMM mainloop: 128x128 tile, BK=64, 4 waves (2x2) --------
// Wave tile 64x64: acc[4][4]. C row = m0+wr*64+mt*16+quad*4+r,
// col = n0+wc*64+nt*16+l16 (verified r2). m97 structure, async LDS staging.
// k-range [kbeg,kend) for split-K callers.
__device__ __forceinline__ void gemm_mainloop(
    const ushort* __restrict__ A, const ushort* __restrict__ Bt,
    int K, int kbeg, int kend, int m0, int n0,
    ushort (*As)[64], ushort (*Bs)[64], v4f acc[4][4])
{
  const int t = threadIdx.x;
  const int lane = t & 63, wave = t >> 6;
  const int wr = wave >> 1, wc = wave & 1;
  const int quad = lane >> 4, l16 = lane & 15;
  const int l8 = lane >> 3, c8 = (lane & 7) * 8;

  const ushort* ap[4];
  const ushort* bp[4];
  ushort* al[4];
  ushort* bl[4];
#pragma unroll
  for (int i = 0; i < 4; ++i) {
    const int row = (wave * 4 + i) * 8 + l8;
    ap[i] = A  + (size_t)(m0 + row) * K + c8;
    bp[i] = Bt + (size_t)(n0 + row) * K + c8;
    al[i] = &As[(wave * 4 + i) * 8][0];
    bl[i] = &Bs[(wave * 4 + i) * 8][0];
  }

  for (int k0 = kbeg; k0 < kend; k0 += 64) {
#pragma unroll
    for (int i = 0; i < 4; ++i) {
      async16(ap[i] + k0, al[i]);
      async16(bp[i] + k0, bl[i]);
    }
    __syncthreads();
#pragma unroll
    for (int ks = 0; ks < 2; ++ks) {
      v8s af[4], bf[4];
#pragma unroll
      for (int i = 0; i < 4; ++i) {
        af[i] = *(const v8s*)&As[wr * 64 + i * 16 + l16][ks * 32 + quad * 8];
        bf[i] = *(const v8s*)&Bs[wc * 64 + i * 16 + l16][ks * 32 + quad * 8];
      }
#pragma unroll
      for (int mt = 0; mt < 4; ++mt)
#pragma unroll
        for (int nt = 0; nt < 4; ++nt)
          acc[mt][nt] = __builtin_amdgcn_mfma_f32_16x16x32_bf16(
              af[mt], bf[nt], acc[mt][nt], 0, 0, 0);
    }
    __syncthreads();
  }
}

// ---------------- QKV GEMM with fused rope/rmsnorm/gate epilogue -----------
// grid (32, 12): sec 0-7 Q heads, 8-9 K heads, 10-11 V heads.
__global__ __launch_bounds__(256) void gemm_qkv_fused(
    const ushort* __restrict__ A, const ushort* __restrict__ Bt,
    const float2* __restrict__ cs, const float* __restrict__ gates,
    const float* __restrict__ ve,
    ushort* __restrict__ qb, ushort* __restrict__ kb, ushort* __restrict__ vb)
{
  __shared__ ushort As[128][64];
  __shared__ ushort Bs[128][64];
  const int m0 = blockIdx.x * 128, n0 = blockIdx.y * 128;
  const int lane = threadIdx.x & 63, wave = threadIdx.x >> 6;
  const int wr = wave >> 1, wc = wave & 1;
  const int quad = lane >> 4, l16 = lane & 15;

  v4f acc[4][4];
#pragma unroll
  for (int i = 0; i < 4; ++i)
#pragma unroll
    for (int j = 0; j < 4; ++j) acc[i][j] = (v4f){0.f, 0.f, 0.f, 0.f};

  gemm_mainloop(A, Bt, 1024, 0, 1024, m0, n0, As, Bs, acc);

  const int sec = blockIdx.y;
  const int head_col = n0 + wc * 64;

  if (sec < 10) {
    const bool isQ = (sec < 8);
    const int h = (head_col - (isQ ? 0 : 1024)) >> 6;
    ushort* dst = isQ ? qb : kb;
    const int ld = isQ ? 1024 : 256;
#pragma unroll
    for (int mt = 0; mt < 4; ++mt)
#pragma unroll
      for (int r = 0; r < 4; ++r) {
        const int row = m0 + wr * 64 + mt * 16 + quad * 4 + r;
        const int s = row & 2047;
        const float2 cs0 = cs[s * 32 + l16];
        const float2 cs1 = cs[s * 32 + 16 + l16];
        const float x10 = acc[mt][0][r], x11 = acc[mt][1][r];
        const float x20 = acc[mt][2][r], x21 = acc[mt][3][r];
        float ss = x10 * x10 + x11 * x11 + x20 * x20 + x21 * x21;
        ss += __shfl_xor(ss, 1);
        ss += __shfl_xor(ss, 2);
        ss += __shfl_xor(ss, 4);
        ss += __shfl_xor(ss, 8);
        const float rs = rsqrtf(ss * (1.0f / 64.0f) + 1e-6f) * 1.2f;
        ushort* dp = dst + (size_t)row * ld + h * 64 + l16;
        dp[0]  = b1((x10 * cs0.x + x20 * cs0.y) * rs);
        dp[16] = b1((x11 * cs1.x + x21 * cs1.y) * rs);
        dp[32] = b1((-x10 * cs0.y + x20 * cs0.x) * rs);
        dp[48] = b1((-x11 * cs1.y + x21 * cs1.x) * rs);
      }
  } else {
    const int kvh = (head_col - 1280) >> 6;
#pragma unroll
    for (int mt = 0; mt < 4; ++mt)
#pragma unroll
      for (int r = 0; r < 4; ++r) {
        const int row = m0 + wr * 64 + mt * 16 + quad * 4 + r;
        const float gate = gates[row * 4 + kvh];
        const float* vep = ve + (size_t)row * 256 + kvh * 64 + l16;
        ushort* dp = vb + (size_t)row * 256 + kvh * 64 + l16;
#pragma unroll
        for (int nt = 0; nt < 4; ++nt)
          dp[nt * 16] = b1(acc[mt][nt][r] + gate * vep[nt * 16]);
      }
  }
}

// ---------------- Wo GEMM, split-K=2: grid (32, 8, 2), atomic fp32 ---------
// d_out zeroed via hipMemsetAsync before launch; each kz adds its half-K
// partial with device-scope atomicAdd (order-independent to ~1e-6).
__global__ __launch_bounds__(256) void gemm_wo(
    const ushort* __restrict__ A, const ushort* __restrict__ Bt,
    float* __restrict__ C)
{
  __shared__ ushort As[128][64];
  __shared__ ushort Bs[128][64];
  const int m0 = blockIdx.x * 128, n0 = blockIdx.y * 128;
  const int kz = blockIdx.z;
  const int lane = threadIdx.x & 63, wave = threadIdx.x >> 6;
  const int wr = wave >> 1, wc = wave & 1;
  const int quad = lane >> 4, l16 = lane & 15;

  v4f acc[4][4];
#pragma unroll
  for (int i = 0; i < 4; ++i)
#pragma unroll
    for (int j = 0; j < 4; ++j) acc[i][j] = (v4f){0.f, 0.f, 0.f, 0.f};

  gemm_mainloop(A, Bt, 1024, kz * 512, kz * 512 + 512, m0, n0, As, Bs, acc);

#pragma unroll
  for (int mt = 0; mt < 4; ++mt)
#pragma unroll
    for (int r = 0; r < 4; ++r) {
      float* cp = C + (size_t)(m0 + wr * 64 + mt * 16 + quad * 4 + r) * 1024
                    + n0 + wc * 64 + l16;
#pragma unroll
      for (int nt = 0; nt < 4; ++nt) atomicAdd(cp + nt * 16, acc[mt][nt][r]);
    }
}

// ---------------- vb [bs][kvh*64+d] -> vtb [b][kvh][d][s] ------------------
__global__ __launch_bounds__(256) void transpose_v(
    const ushort* __restrict__ vb, ushort* __restrict__ vtb)
{
  __shared__ ushort L[64][72];
  const int s0 = blockIdx.x * 64, kvh = blockIdx.y, b = blockIdx.z;
  const int t = threadIdx.x;
#pragma unroll
  for (int i = 0; i < 2; ++i) {
    const int cc = t + i * 256;
    const int srow = cc >> 3, c8 = (cc & 7) * 8;
    *(int4*)&L[srow][c8] =
        *(const int4*)(vb + ((size_t)(b * 2048 + s0 + srow)) * 256 + kvh * 64 + c8);
  }
  __syncthreads();
#pragma unroll
  for (int i = 0; i < 2; ++i) {
    const int cc = t + i * 256;
    const int drow = cc >> 3, s8 = (cc & 7) * 8;
    ushort w[8];
#pragma unroll
    for (int jj = 0; jj < 8; ++jj) w[jj] = L[s8 + jj][drow];
    *(int4*)(vtb + ((size_t)((b * 4 + kvh) * 64 + drow)) * 2048 + s0 + s8) =
        *(int4*)w;
  }
}

// ---------------- MFMA flash attention, fixed-max softmax ------------------
// p = exp2(s*0.125*log2e - 12*log2e), exact shift of softmax (bound 11.52).
__global__ __launch_bounds__(256) void attn_mfma(
    const ushort* __restrict__ qb, const ushort* __restrict__ kb,
    const ushort* __restrict__ vtb, ushort* __restrict__ yb,
    const int* __restrict__ wptr)
{
  __shared__ ushort Ks[64][72];
  __shared__ ushort Vt[80][72];
  __shared__ ushort Ps[128][72];
  const int qt = blockIdx.x, h = blockIdx.y, b = blockIdx.z;
  const int kvh = h >> 2, q0 = qt * 128;
  const int t = threadIdx.x, lane = t & 63, wave = t >> 6;
  const int quad = lane >> 4, l16 = lane & 15;
  const int Wwin = *wptr;

  v8s qf[2][2];
#pragma unroll
  for (int s = 0; s < 2; ++s) {
    const ushort* qp = qb + ((size_t)(b * 2048 + q0 + wave * 32 + s * 16 + l16)) * 1024
                          + h * 64 + quad * 8;
    qf[s][0] = *(const v8s*)qp;
    qf[s][1] = *(const v8s*)(qp + 32);
  }

  if (t < 128) {
    const int row = 64 + (t >> 3), c8 = (t & 7) * 8;
    const int v = (row == 64) ? 0x3F803F80 : 0;
    int4 w; w.x = v; w.y = v; w.z = v; w.w = v;
    *(int4*)&Vt[row][c8] = w;
  }

  v4f o[2][5];
#pragma unroll
  for (int s = 0; s < 2; ++s)
#pragma unroll
    for (int d = 0; d < 5; ++d) o[s][d] = (v4f){0.f, 0.f, 0.f, 0.f};

  const int lo = q0 - Wwin + 1;
  const int kt0 = (lo > 0) ? (lo >> 6) : 0;
  const int kt1 = (q0 + 127) >> 6;

  for (int kt = kt0; kt <= kt1; ++kt) {
#pragma unroll
    for (int i = 0; i < 2; ++i) {
      const int cc = t + i * 256;
      const int r8 = cc >> 3, c8 = (cc & 7) * 8;
      *(int4*)&Ks[r8][c8] =
          *(const int4*)(kb + ((size_t)(b * 2048 + kt * 64 + r8)) * 256 + kvh * 64 + c8);
      *(int4*)&Vt[r8][c8] =
          *(const int4*)(vtb + ((size_t)((b * 4 + kvh) * 64 + r8)) * 2048 + kt * 64 + c8);
    }
    __syncthreads();

    const bool needs_mask = (kt * 64 + 63 > q0) || (kt * 64 < q0 + 128 - Wwin);

#pragma unroll
    for (int s = 0; s < 2; ++s) {
      const int qrow = q0 + wave * 32 + s * 16 + l16;
      ushort* prow = &Ps[wave * 32 + s * 16 + l16][0];
#pragma unroll
      for (int nt = 0; nt < 4; ++nt) {
        v8s kf0 = *(const v8s*)&Ks[nt * 16 + l16][quad * 8];
        v8s kf1 = *(const v8s*)&Ks[nt * 16 + l16][32 + quad * 8];
        v4f st = (v4f){0.f, 0.f, 0.f, 0.f};
        st = __builtin_amdgcn_mfma_f32_16x16x32_bf16(kf0, qf[s][0], st, 0, 0, 0);
        st = __builtin_amdgcn_mfma_f32_16x16x32_bf16(kf1, qf[s][1], st, 0, 0, 0);
        float p[4];
#pragma unroll
        for (int r = 0; r < 4; ++r) {
          p[r] = exp2f(fmaf(st[r], 0.18033688011f, -17.31234049107f));
          if (needs_mask) {
            const int k = kt * 64 + nt * 16 + quad * 4 + r;
            const bool ok = (k <= qrow) && (k > qrow - Wwin);
            p[r] = ok ? p[r] : 0.0f;
          }
        }
        uint2 w;
        w.x = bpack(p[0], p[1]);
        w.y = bpack(p[2], p[3]);
        *(uint2*)(prow + nt * 16 + quad * 4) = w;
      }
    }

    v8s pf[2][2];
#pragma unroll
    for (int s = 0; s < 2; ++s) {
      pf[s][0] = *(const v8s*)&Ps[wave * 32 + s * 16 + l16][quad * 8];
      pf[s][1] = *(const v8s*)&Ps[wave * 32 + s * 16 + l16][32 + quad * 8];
    }
#pragma unroll
    for (int dt = 0; dt < 5; ++dt) {
      v8s vf0 = *(const v8s*)&Vt[dt * 16 + l16][quad * 8];
      v8s vf1 = *(const v8s*)&Vt[dt * 16 + l16][32 + quad * 8];
#pragma unroll
      for (int s = 0; s < 2; ++s) {
        o[s][dt] = __builtin_amdgcn_mfma_f32_16x16x32_bf16(pf[s][0], vf0, o[s][dt], 0, 0, 0);
        o[s][dt] = __builtin_amdgcn_mfma_f32_16x16x32_bf16(pf[s][1], vf1, o[s][dt], 0, 0, 0);
      }
    }
    __syncthreads();
  }

#pragma unroll
  for (int s = 0; s < 2; ++s)
#pragma unroll
    for (int r = 0; r < 4; ++r) {
      const float l = __shfl(o[s][4][r], lane & 48);
      const float inv = 1.0f / l;
      ushort* yp = yb + ((size_t)(b * 2048 + q0 + wave * 32 + s * 16 + quad * 4 + r)) * 1024
                      + h * 64 + l16;
#pragma unroll
      for (int dt = 0; dt < 4; ++dt) yp[dt * 16] = b1(o[s][dt][r] * inv);
    }
}

// ---------------------------------------------------------------------------
extern "C" void kernel_launch(void* const* d_in, const int* in_sizes, int n_in,
                              void* d_out, int out_size, void* d_ws, size_t ws_size,
                              hipStream_t stream)
{
  const float* x    = (const float*)d_in[0];
  const float* ve   = (const float*)d_in[1];
  const float* cosp = (const float*)d_in[2];
  const float* sinp = (const float*)d_in[3];
  const float* Wq   = (const float*)d_in[4];
  const float* Wk   = (const float*)d_in[5];
  const float* Wv   = (const float*)d_in[6];
  const float* Wo   = (const float*)d_in[7];
  const float* Wg   = (const float*)d_in[8];
  const int*   win  = (const int*)d_in[9];
  float* out = (float*)d_out;

  char* p = (char*)d_ws;
  ushort* xb    = (ushort*)p;  p += (size_t)4194304 * 2;      //  8 MB
  ushort* qb    = (ushort*)p;  p += (size_t)4194304 * 2;      //  8 MB
  ushort* yb    = (ushort*)p;  p += (size_t)4194304 * 2;      //  8 MB
  ushort* kb    = (ushort*)p;  p += (size_t)1048576 * 2;      //  2 MB
  ushort* vb    = (ushort*)p;  p += (size_t)1048576 * 2;      //  2 MB
  ushort* vtb   = (ushort*)p;  p += (size_t)1048576 * 2;      //  2 MB
  ushort* Wqkvt = (ushort*)p;  p += (size_t)1536 * 1024 * 2;  //  3 MB
  ushort* Wot   = (ushort*)p;  p += (size_t)1048576 * 2;      //  2 MB
  float2* cs    = (float2*)p;  p += (size_t)65536 * 8;        // .5 MB
  float*  gates = (float*)p;                                  // 64 KB

  // zero d_out for split-K atomic accumulation (graph-capturable)
  hipMemsetAsync(out, 0, (size_t)out_size * sizeof(float), stream);

  prep_all<<<6912, 256, 0, stream>>>(
      x, xb, Wg, gates, cosp, sinp, cs, Wq, Wk, Wv, Wo,
      Wqkvt, Wqkvt + (size_t)1024 * 1024, Wqkvt + (size_t)1280 * 1024, Wot);

  gemm_qkv_fused<<<dim3(32, 12), 256, 0, stream>>>(xb, Wqkvt, cs, gates, ve,
                                                   qb, kb, vb);
  transpose_v<<<dim3(32, 4, 2), 256, 0, stream>>>(vb, vtb);

  attn_mfma<<<dim3(16, 16, 2), 256, 0, stream>>>(qb, kb, vtb, yb, win);

  gemm_wo<<<dim3(32, 8, 2), 256, 0, stream>>>(yb, Wot, out);
}

// Round 10
// 177.915 us; speedup vs baseline: 1.1003x; 1.1003x over previous
//
#include <hip/hip_runtime.h>
#include <hip/hip_bf16.h>
#include <cstddef>
#include <cstdint>

// B=2, S=2048, D=1024, H=16, KVH=4, hd=64. window from d_in[9].
// r10 = exact revert to the r6 measured optimum (174.5 us):
//  - m97-structure 128x128/BK=64 async-LDS GEMMs, plain epilogues
//  - fused rope/rmsnorm/gate in QKV epilogue, separate transpose_v
//  - fixed-max softmax MFMA attention (exp2, b1 pack)
// r7 (64-tile), r8 (union-LDS fusion), r9 (split-K atomics) all regressed.

typedef short v8s __attribute__((ext_vector_type(8)));
typedef float v4f __attribute__((ext_vector_type(4)));

// Exact RNE fp32->bf16 for FINITE values (no NaN path): 3 VALU ops.
__device__ __forceinline__ ushort b1(float a) {
  uint u = __float_as_uint(a);
  return (ushort)((u + 0x7FFFu + ((u >> 16) & 1u)) >> 16);
}
__device__ __forceinline__ uint bpack(float lo, float hi) {
  uint ul = __float_as_uint(lo), uh = __float_as_uint(hi);
  ul = (ul + 0x7FFFu + ((ul >> 16) & 1u)) >> 16;
  uh = (uh + 0x7FFFu + ((uh >> 16) & 1u)) & 0xFFFF0000u;
  return ul | uh;
}

// async global->LDS 16B/lane (wave-uniform LDS base + lane*16).
__device__ __forceinline__ void async16(const ushort* g, ushort* l) {
  __builtin_amdgcn_global_load_lds(
      (__attribute__((address_space(1))) void*)(uintptr_t)(const void*)g,
      (__attribute__((address_space(3))) void*)(uintptr_t)(void*)l, 16, 0, 0);
}

// ---------------- merged prep: x-cvt+gates | cs pack | 4 weight transposes --
__global__ __launch_bounds__(256) void prep_all(
    const float* __restrict__ x, ushort* __restrict__ xb,
    const float* __restrict__ Wg, float* __restrict__ gates,
    const float* __restrict__ cosp, const float* __restrict__ sinp,
    float2* __restrict__ cs,
    const float* __restrict__ Wq, const float* __restrict__ Wk,
    const float* __restrict__ Wv, const float* __restrict__ Wo,
    ushort* __restrict__ Wqt, ushort* __restrict__ Wkt,
    ushort* __restrict__ Wvt, ushort* __restrict__ Wot)
{
  const int bx = blockIdx.x, t = threadIdx.x;
  if (bx < 4096) {
    const float* row = x + (size_t)bx * 1024;
    float4 v = *(const float4*)(row + t * 4);
    ushort4 o;
    o.x = b1(v.x); o.y = b1(v.y); o.z = b1(v.z); o.w = b1(v.w);
    *(ushort4*)(xb + (size_t)bx * 1024 + t * 4) = o;
    if (t < 4) {
      float g = 0.f;
#pragma unroll
      for (int i = 0; i < 12; ++i) g += row[i] * Wg[i * 4 + t];
      gates[bx * 4 + t] = 3.0f / (1.0f + __expf(-g));
    }
    return;
  }
  if (bx < 4352) {
    const int i = (bx - 4096) * 256 + t;
    cs[i] = make_float2(cosp[i], sinp[i]);
    return;
  }
  __shared__ ushort tile[32][33];
  int u = bx - 4352;
  const float* W; ushort* Wt; int N, xx, yy;
  if (u < 1024)      { W = Wq; Wt = Wqt; N = 1024; xx = u & 31; yy = u >> 5; }
  else if (u < 2048) { u -= 1024; W = Wo; Wt = Wot; N = 1024; xx = u & 31; yy = u >> 5; }
  else if (u < 2304) { u -= 2048; W = Wk; Wt = Wkt; N = 256;  xx = u & 7;  yy = u >> 3; }
  else               { u -= 2304; W = Wv; Wt = Wvt; N = 256;  xx = u & 7;  yy = u >> 3; }
  const int n0 = xx * 32, k0 = yy * 32;
  const int tx = t & 31, ty = t >> 5;
#pragma unroll
  for (int i = 0; i < 4; ++i) {
    const int k = ty + i * 8;
    tile[k][tx] = b1(W[(size_t)(k0 + k) * N + n0 + tx]);
  }
  __syncthreads();
#pragma unroll
  for (int i = 0; i < 4; ++i) {
    const int n = ty + i * 8;
    Wt[(size_t)(n0 + n) * 1024 + k0 + tx] = tile[tx][n];
  }
}

// ---------------- GEMM mainloop: 128x128 tile, BK=64, 4 waves (2x2) --------
// Wave tile 64x64: acc[4][4]. C row = m0+wr*64+mt*16+quad*4+r,
// col = n0+wc*64+nt*16+l16 (verified r2). m97 structure, async LDS staging.
__device__ __forceinline__ void gemm_mainloop(
    const ushort* __restrict__ A, const ushort* __restrict__ Bt,
    int K, int m0, int n0, ushort (*As)[64], ushort (*Bs)[64],
    v4f acc[4][4])
{
  const int t = threadIdx.x;
  const int lane = t & 63, wave = t >> 6;
  const int wr = wave >> 1, wc = wave & 1;
  const int quad = lane >> 4, l16 = lane & 15;
  const int l8 = lane >> 3, c8 = (lane & 7) * 8;

  const ushort* ap[4];
  const ushort* bp[4];
  ushort* al[4];
  ushort* bl[4];
#pragma unroll
  for (int i = 0; i < 4; ++i) {
    const int row = (wave * 4 + i) * 8;
    ap[i] = A  + (size_t)(m0 + row + l8) * K + c8;
    bp[i] = Bt + (size_t)(n0 + row + l8) * K + c8;
    al[i] = &As[row][0];
    bl[i] = &Bs[row][0];
  }

  for (int k0 = 0; k0 < K; k0 += 64) {
#pragma unroll
    for (int i = 0; i < 4; ++i) {
      async16(ap[i] + k0, al[i]);
      async16(bp[i] + k0, bl[i]);
    }
    __syncthreads();
#pragma unroll
    for (int ks = 0; ks < 2; ++ks) {
      v8s af[4], bf[4];
#pragma unroll
      for (int i = 0; i < 4; ++i) {
        af[i] = *(const v8s*)&As[wr * 64 + i * 16 + l16][ks * 32 + quad * 8];
        bf[i] = *(const v8s*)&Bs[wc * 64 + i * 16 + l16][ks * 32 + quad * 8];
      }
#pragma unroll
      for (int mt = 0; mt < 4; ++mt)
#pragma unroll
        for (int nt = 0; nt < 4; ++nt)
          acc[mt][nt] = __builtin_amdgcn_mfma_f32_16x16x32_bf16(
              af[mt], bf[nt], acc[mt][nt], 0, 0, 0);
    }
    __syncthreads();
  }
}

// ---------------- QKV GEMM with fused rope/rmsnorm/gate epilogue -----------
__global__ __launch_bounds__(256) void gemm_qkv_fused(
    const ushort* __restrict__ A, const ushort* __restrict__ Bt,
    const float2* __restrict__ cs, const float* __restrict__ gates,
    const float* __restrict__ ve,
    ushort* __restrict__ qb, ushort* __restrict__ kb, ushort* __restrict__ vb)
{
  __shared__ ushort As[128][64];
  __shared__ ushort Bs[128][64];
  const int m0 = blockIdx.x * 128, n0 = blockIdx.y * 128;
  const int lane = threadIdx.x & 63, wave = threadIdx.x >> 6;
  const int wr = wave >> 1, wc = wave & 1;
  const int quad = lane >> 4, l16 = lane & 15;

  v4f acc[4][4];
#pragma unroll
  for (int i = 0; i < 4; ++i)
#pragma unroll
    for (int j = 0; j < 4; ++j) acc[i][j] = (v4f){0.f, 0.f, 0.f, 0.f};

  gemm_mainloop(A, Bt, 1024, m0, n0, As, Bs, acc);

  const int sec = blockIdx.y;
  const int head_col = n0 + wc * 64;

  if (sec < 10) {
    const bool isQ = (sec < 8);
    const int h = (head_col - (isQ ? 0 : 1024)) >> 6;
    ushort* dst = isQ ? qb : kb;
    const int ld = isQ ? 1024 : 256;
#pragma unroll
    for (int mt = 0; mt < 4; ++mt)
#pragma unroll
      for (int r = 0; r < 4; ++r) {
        const int row = m0 + wr * 64 + mt * 16 + quad * 4 + r;
        const int s = row & 2047;
        const float2 cs0 = cs[s * 32 + l16];
        const float2 cs1 = cs[s * 32 + 16 + l16];
        const float x10 = acc[mt][0][r], x11 = acc[mt][1][r];
        const float x20 = acc[mt][2][r], x21 = acc[mt][3][r];
        float ss = x10 * x10 + x11 * x11 + x20 * x20 + x21 * x21;
        ss += __shfl_xor(ss, 1);
        ss += __shfl_xor(ss, 2);
        ss += __shfl_xor(ss, 4);
        ss += __shfl_xor(ss, 8);
        const float rs = rsqrtf(ss * (1.0f / 64.0f) + 1e-6f) * 1.2f;
        ushort* dp = dst + (size_t)row * ld + h * 64 + l16;
        dp[0]  = b1((x10 * cs0.x + x20 * cs0.y) * rs);
        dp[16] = b1((x11 * cs1.x + x21 * cs1.y) * rs);
        dp[32] = b1((-x10 * cs0.y + x20 * cs0.x) * rs);
        dp[48] = b1((-x11 * cs1.y + x21 * cs1.x) * rs);
      }
  } else {
    const int kvh = (head_col - 1280) >> 6;
#pragma unroll
    for (int mt = 0; mt < 4; ++mt)
#pragma unroll
      for (int r = 0; r < 4; ++r) {
        const int row = m0 + wr * 64 + mt * 16 + quad * 4 + r;
        const float gate = gates[row * 4 + kvh];
        const float* vep = ve + (size_t)row * 256 + kvh * 64 + l16;
        ushort* dp = vb + (size_t)row * 256 + kvh * 64 + l16;
#pragma unroll
        for (int nt = 0; nt < 4; ++nt)
          dp[nt * 16] = b1(acc[mt][nt][r] + gate * vep[nt * 16]);
      }
  }
}

// ---------------- Wo GEMM: grid (32, 8), fp32 epilogue ---------------------
__global__ __launch_bounds__(256) void gemm_wo(
    const ushort* __restrict__ A, const ushort* __restrict__ Bt,
    float* __restrict__ C)
{
  __shared__ ushort As[128][64];
  __shared__ ushort Bs[128][64];
  const int m0 = blockIdx.x * 128, n0 = blockIdx.y * 128;
  const int lane = threadIdx.x & 63, wave = threadIdx.x >> 6;
  const int wr = wave >> 1, wc = wave & 1;
  const int quad = lane >> 4, l16 = lane & 15;

  v4f acc[4][4];
#pragma unroll
  for (int i = 0; i < 4; ++i)
#pragma unroll
    for (int j = 0; j < 4; ++j) acc[i][j] = (v4f){0.f, 0.f, 0.f, 0.f};

  gemm_mainloop(A, Bt, 1024, m0, n0, As, Bs, acc);

#pragma unroll
  for (int mt = 0; mt < 4; ++mt)
#pragma unroll
    for (int r = 0; r < 4; ++r) {
      float* cp = C + (size_t)(m0 + wr * 64 + mt * 16 + quad * 4 + r) * 1024
                    + n0 + wc * 64 + l16;
#pragma unroll
      for (int nt = 0; nt < 4; ++nt) cp[nt * 16] = acc[mt][nt][r];
    }
}

// ---------------- vb [bs][kvh*64+d] -> vtb [b][kvh][d][s] ------------------
__global__ __launch_bounds__(256) void transpose_v(
    const ushort* __restrict__ vb, ushort* __restrict__ vtb)
{
  __shared__ ushort L[64][72];
  const int s0 = blockIdx.x * 64, kvh = blockIdx.y, b = blockIdx.z;
  const int t = threadIdx.x;
#pragma unroll
  for (int i = 0; i < 2; ++i) {
    const int cc = t + i * 256;
    const int srow = cc >> 3, c8 = (cc & 7) * 8;
    *(int4*)&L[srow][c8] =
        *(const int4*)(vb + ((size_t)(b * 2048 + s0 + srow)) * 256 + kvh * 64 + c8);
  }
  __syncthreads();
#pragma unroll
  for (int i = 0; i < 2; ++i) {
    const int cc = t + i * 256;
    const int drow = cc >> 3, s8 = (cc & 7) * 8;
    ushort w[8];
#pragma unroll
    for (int jj = 0; jj < 8; ++jj) w[jj] = L[s8 + jj][drow];
    *(int4*)(vtb + ((size_t)((b * 4 + kvh) * 64 + drow)) * 2048 + s0 + s8) =
        *(int4*)w;
  }
}

// ---------------- MFMA flash attention, fixed-max softmax ------------------
// p = exp2(s*0.125*log2e - 12*log2e), exact shift of softmax (bound 11.52).
__global__ __launch_bounds__(256) void attn_mfma(
    const ushort* __restrict__ qb, const ushort* __restrict__ kb,
    const ushort* __restrict__ vtb, ushort* __restrict__ yb,
    const int* __restrict__ wptr)
{
  __shared__ ushort Ks[64][72];
  __shared__ ushort Vt[80][72];
  __shared__ ushort Ps[128][72];
  const int qt = blockIdx.x, h = blockIdx.y, b = blockIdx.z;
  const int kvh = h >> 2, q0 = qt * 128;
  const int t = threadIdx.x, lane = t & 63, wave = t >> 6;
  const int quad = lane >> 4, l16 = lane & 15;
  const int Wwin = *wptr;

  v8s qf[2][2];
#pragma unroll
  for (int s = 0; s < 2; ++s) {
    const ushort* qp = qb + ((size_t)(b * 2048 + q0 + wave * 32 + s * 16 + l16)) * 1024
                          + h * 64 + quad * 8;
    qf[s][0] = *(const v8s*)qp;
    qf[s][1] = *(const v8s*)(qp + 32);
  }

  if (t < 128) {
    const int row = 64 + (t >> 3), c8 = (t & 7) * 8;
    const int v = (row == 64) ? 0x3F803F80 : 0;
    int4 w; w.x = v; w.y = v; w.z = v; w.w = v;
    *(int4*)&Vt[row][c8] = w;
  }

  v4f o[2][5];
#pragma unroll
  for (int s = 0; s < 2; ++s)
#pragma unroll
    for (int d = 0; d < 5; ++d) o[s][d] = (v4f){0.f, 0.f, 0.f, 0.f};

  const int lo = q0 - Wwin + 1;
  const int kt0 = (lo > 0) ? (lo >> 6) : 0;
  const int kt1 = (q0 + 127) >> 6;

  for (int kt = kt0; kt <= kt1; ++kt) {
#pragma unroll
    for (int i = 0; i < 2; ++i) {
      const int cc = t + i * 256;
      const int r8 = cc >> 3, c8 = (cc & 7) * 8;
      *(int4*)&Ks[r8][c8] =
          *(const int4*)(kb + ((size_t)(b * 2048 + kt * 64 + r8)) * 256 + kvh * 64 + c8);
      *(int4*)&Vt[r8][c8] =
          *(const int4*)(vtb + ((size_t)((b * 4 + kvh) * 64 + r8)) * 2048 + kt * 64 + c8);
    }
    __syncthreads();

    const bool needs_mask = (kt * 64 + 63 > q0) || (kt * 64 < q0 + 128 - Wwin);

#pragma unroll
    for (int s = 0; s < 2; ++s) {
      const int qrow = q0 + wave * 32 + s * 16 + l16;
      ushort* prow = &Ps[wave * 32 + s * 16 + l16][0];
#pragma unroll
      for (int nt = 0; nt < 4; ++nt) {
        v8s kf0 = *(const v8s*)&Ks[nt * 16 + l16][quad * 8];
        v8s kf1 = *(const v8s*)&Ks[nt * 16 + l16][32 + quad * 8];
        v4f st = (v4f){0.f, 0.f, 0.f, 0.f};
        st = __builtin_amdgcn_mfma_f32_16x16x32_bf16(kf0, qf[s][0], st, 0, 0, 0);
        st = __builtin_amdgcn_mfma_f32_16x16x32_bf16(kf1, qf[s][1], st, 0, 0, 0);
        float p[4];
#pragma unroll
        for (int r = 0; r < 4; ++r) {
          p[r] = exp2f(fmaf(st[r], 0.18033688011f, -17.31234049107f));
          if (needs_mask) {
            const int k = kt * 64 + nt * 16 + quad * 4 + r;
            const bool ok = (k <= qrow) && (k > qrow - Wwin);
            p[r] = ok ? p[r] : 0.0f;
          }
        }
        uint2 w;
        w.x = bpack(p[0], p[1]);
        w.y = bpack(p[2], p[3]);
        *(uint2*)(prow + nt * 16 + quad * 4) = w;
      }
    }

    v8s pf[2][2];
#pragma unroll
    for (int s = 0; s < 2; ++s) {
      pf[s][0] = *(const v8s*)&Ps[wave * 32 + s * 16 + l16][quad * 8];
      pf[s][1] = *(const v8s*)&Ps[wave * 32 + s * 16 + l16][32 + quad * 8];
    }
#pragma unroll
    for (int dt = 0; dt < 5; ++dt) {
      v8s vf0 = *(const v8s*)&Vt[dt * 16 + l16][quad * 8];
      v8s vf1 = *(const v8s*)&Vt[dt * 16 + l16][32 + quad * 8];
#pragma unroll
      for (int s = 0; s < 2; ++s) {
        o[s][dt] = __builtin_amdgcn_mfma_f32_16x16x32_bf16(pf[s][0], vf0, o[s][dt], 0, 0, 0);
        o[s][dt] = __builtin_amdgcn_mfma_f32_16x16x32_bf16(pf[s][1], vf1, o[s][dt], 0, 0, 0);
      }
    }
    __syncthreads();
  }

#pragma unroll
  for (int s = 0; s < 2; ++s)
#pragma unroll
    for (int r = 0; r < 4; ++r) {
      const float l = __shfl(o[s][4][r], lane & 48);
      const float inv = 1.0f / l;
      ushort* yp = yb + ((size_t)(b * 2048 + q0 + wave * 32 + s * 16 + quad * 4 + r)) * 1024
                      + h * 64 + l16;
#pragma unroll
      for (int dt = 0; dt < 4; ++dt) yp[dt * 16] = b1(o[s][dt][r] * inv);
    }
}

// ---------------------------------------------------------------------------
extern "C" void kernel_launch(void* const* d_in, const int* in_sizes, int n_in,
                              void* d_out, int out_size, void* d_ws, size_t ws_size,
                              hipStream_t stream)
{
  const float* x    = (const float*)d_in[0];
  const float* ve   = (const float*)d_in[1];
  const float* cosp = (const float*)d_in[2];
  const float* sinp = (const float*)d_in[3];
  const float* Wq   = (const float*)d_in[4];
  const float* Wk   = (const float*)d_in[5];
  const float* Wv   = (const float*)d_in[6];
  const float* Wo   = (const float*)d_in[7];
  const float* Wg   = (const float*)d_in[8];
  const int*   win  = (const int*)d_in[9];
  float* out = (float*)d_out;

  char* p = (char*)d_ws;
  ushort* xb    = (ushort*)p;  p += (size_t)4194304 * 2;      //  8 MB
  ushort* qb    = (ushort*)p;  p += (size_t)4194304 * 2;      //  8 MB
  ushort* yb    = (ushort*)p;  p += (size_t)4194304 * 2;      //  8 MB
  ushort* kb    = (ushort*)p;  p += (size_t)1048576 * 2;      //  2 MB
  ushort* vb    = (ushort*)p;  p += (size_t)1048576 * 2;      //  2 MB
  ushort* vtb   = (ushort*)p;  p += (size_t)1048576 * 2;      //  2 MB
  ushort* Wqkvt = (ushort*)p;  p += (size_t)1536 * 1024 * 2;  //  3 MB
  ushort* Wot   = (ushort*)p;  p += (size_t)1048576 * 2;      //  2 MB
  float2* cs    = (float2*)p;  p += (size_t)65536 * 8;        // .5 MB
  float*  gates = (float*)p;                                  // 64 KB

  prep_all<<<6912, 256, 0, stream>>>(
      x, xb, Wg, gates, cosp, sinp, cs, Wq, Wk, Wv, Wo,
      Wqkvt, Wqkvt + (size_t)1024 * 1024, Wqkvt + (size_t)1280 * 1024, Wot);

  gemm_qkv_fused<<<dim3(32, 12), 256, 0, stream>>>(xb, Wqkvt, cs, gates, ve,
                                                   qb, kb, vb);
  transpose_v<<<dim3(32, 4, 2), 256, 0, stream>>>(vb, vtb);

  attn_mfma<<<dim3(16, 16, 2), 256, 0, stream>>>(qb, kb, vtb, yb, win);

  gemm_wo<<<dim3(32, 8), 256, 0, stream>>>(yb, Wot, out);
}